// Round 6
// baseline (255.984 us; speedup 1.0000x reference)
//
#include <hip/hip_runtime.h>
#include <hip/hip_bf16.h>

#define NROWS 65536   // B*H*W*n
#define DIM   512
#define SCALE_ 0.125f // 64^-0.5

typedef short bf16x8 __attribute__((ext_vector_type(8)));
typedef unsigned short u16x8 __attribute__((ext_vector_type(8)));
typedef float f32x4 __attribute__((ext_vector_type(4)));

__device__ __forceinline__ unsigned short f2bf(float f) {
  union { float f; unsigned u; } v; v.f = f;
  unsigned r = v.u + 0x7FFFu + ((v.u >> 16) & 1u);  // RNE
  return (unsigned short)(r >> 16);
}

// async global->LDS, 16B per lane. LDS dest is wave-uniform base + lane*16 (HW).
#define GLL16(gptr, lptr) \
  __builtin_amdgcn_global_load_lds((const __attribute__((address_space(1))) void*)(gptr), \
                                   (__attribute__((address_space(3))) void*)(lptr), 16, 0, 0)
#define VMCNT(n) asm volatile("s_waitcnt vmcnt(" #n ")" ::: "memory")
#define LGKM0    asm volatile("s_waitcnt lgkmcnt(0)" ::: "memory")

// ---------------- prep: x f32->bf16 (blocks 0..16383) + weights transpose (16384..20479) ----
__global__ void prep_kernel(const float* __restrict__ x,
                            const float* __restrict__ wqkv,
                            const float* __restrict__ wout,
                            unsigned short* __restrict__ xb,
                            unsigned short* __restrict__ wqkvT,
                            unsigned short* __restrict__ woutT) {
  if (blockIdx.x < 16384) {
    size_t i = ((size_t)blockIdx.x * 256 + threadIdx.x) * 8;
    float4 a = *(const float4*)(x + i);
    float4 b = *(const float4*)(x + i + 4);
    u16x8 p;
    p[0] = f2bf(a.x); p[1] = f2bf(a.y); p[2] = f2bf(a.z); p[3] = f2bf(a.w);
    p[4] = f2bf(b.x); p[5] = f2bf(b.y); p[6] = f2bf(b.z); p[7] = f2bf(b.w);
    *(u16x8*)(xb + i) = p;
  } else {
    int idx = (blockIdx.x - 16384) * 256 + threadIdx.x;
    if (idx < 1536 * 512) {
      int j = idx >> 9, c = idx & 511;
      wqkvT[idx] = f2bf(wqkv[(size_t)c * 1536 + j]);
    } else {
      int k2 = idx - 1536 * 512;
      int n = k2 >> 9, c = k2 & 511;
      woutT[k2] = f2bf(wout[(size_t)c * 512 + n]);
    }
  }
}

// ---------------- K1: fused QKV GEMM + attention ----------------
// grid 4096 = 512 mtiles x 8 heads. 256 thr = 4 waves; wave w owns rows [32w,32w+32)
// x all 192 cols (acc[2][12]). BK=32, dbuf 2x20KB = 40KB -> 4 blocks/CU.
// Epilogue fully wave-local (1 block barrier total).
__global__ __launch_bounds__(256, 4)
void qkv_attn_kernel(const unsigned short* __restrict__ xb,
                     const float* __restrict__ mask,
                     const unsigned short* __restrict__ wqkvT,
                     unsigned short* __restrict__ attn_out) {
  // buf i at i*20480: A[128][32swz] 8KB + B[192][32swz] 12KB.
  // Epilogue: per-wave 10KB region at w*10240: Qs[32][64]swz | Ks @+4096,
  // then (after QK^T) VT[64][40] @+0 | Pl 2x[16][40] @+5120.
  __shared__ __align__(16) unsigned char smem[40960];

  const int t = threadIdx.x;
  const int lane = t & 63, w = t >> 6;
  const int fr = lane & 15, fq = lane >> 4;
  const int l4 = lane >> 2, ls = lane & 3;
  // stage-side source k-slot so that LDS[row][s] = src[row][s ^ swz(row)],
  // swz(row) = (row ^ (row>>2)) & 3  (kills the r/r+4/r+8/r+12 4-way conflict)
  const int sigma = ((ls ^ (l4 ^ (l4 >> 2))) & 3) * 8;           // bf16 units
  const unsigned rko = ((unsigned)(fq ^ ((fr ^ (fr >> 2)) & 3))) << 4;

  const int per = gridDim.x >> 3;
  const int lin = (blockIdx.x & 7) * per + (blockIdx.x >> 3);
  const int mtile = lin >> 3, head = lin & 7;
  const int r0 = mtile * 128;

  f32x4 acc[2][12];
  const f32x4 z4 = {0.f, 0.f, 0.f, 0.f};
  #pragma unroll
  for (int m = 0; m < 2; ++m)
    #pragma unroll
    for (int n = 0; n < 12; ++n) acc[m][n] = z4;

  auto STAGE = [&](int buf, int kt2) {   // 5 GLL per wave (2 A + 3 B)
    unsigned char* base = smem + buf * 20480;
    const int k0 = kt2 * 32;
    #pragma unroll
    for (int i = 0; i < 2; ++i) {
      int c = w * 2 + i;                 // A chunk: rows 16c..16c+15
      GLL16(xb + (size_t)(r0 + c * 16 + l4) * 512 + k0 + sigma, base + c * 1024);
    }
    #pragma unroll
    for (int i = 0; i < 3; ++i) {
      int c = w * 3 + i;                 // B chunk: rows 16c..16c+15 of 192
      int n = c * 16 + l4;
      int jg = ((n >> 6) << 9) + head * 64 + (n & 63);
      GLL16(wqkvT + (size_t)jg * 512 + k0 + sigma, base + 8192 + c * 1024);
    }
  };

  auto COMPUTE = [&](int buf) {          // 14 ds_read_b128 + 24 MFMA per wave
    unsigned char* Ab = smem + buf * 20480;
    unsigned char* Bb = Ab + 8192;
    bf16x8 a[2];
    #pragma unroll
    for (int m = 0; m < 2; ++m)
      a[m] = *(const bf16x8*)(Ab + (unsigned)(w * 32 + m * 16 + fr) * 64 + rko);
    #pragma unroll
    for (int nh = 0; nh < 4; ++nh) {
      bf16x8 b[3];
      #pragma unroll
      for (int i = 0; i < 3; ++i)
        b[i] = *(const bf16x8*)(Bb + (unsigned)((nh * 3 + i) * 16 + fr) * 64 + rko);
      __builtin_amdgcn_s_setprio(1);
      #pragma unroll
      for (int m = 0; m < 2; ++m)
        #pragma unroll
        for (int i = 0; i < 3; ++i)
          acc[m][nh * 3 + i] =
              __builtin_amdgcn_mfma_f32_16x16x32_bf16(a[m], b[i], acc[m][nh * 3 + i], 0, 0, 0);
      __builtin_amdgcn_s_setprio(0);
    }
  };

  STAGE(0, 0);
  VMCNT(0);
  __syncthreads();
  for (int kt = 0; kt < 16; ++kt) {
    if (kt < 15) STAGE((kt + 1) & 1, kt + 1);
    COMPUTE(kt & 1);
    VMCNT(0);
    __syncthreads();
  }

  // ---------------- epilogue: fully wave-local ----------------
  unsigned char* wreg = smem + w * 10240;
  unsigned short* Qs = (unsigned short*)wreg;            // [32][64] swz, 4KB
  unsigned short* Ks = (unsigned short*)(wreg + 4096);   // [32][64] swz, 4KB

  // mask preload first: latency hides under the spill below
  float mreg[2][4];
  #pragma unroll
  for (int pr = 0; pr < 2; ++pr) {
    #pragma unroll
    for (int r = 0; r < 4; ++r) {
      int q = fq * 4 + r;
      int Pg = mtile * 16 + w * 4 + pr * 2 + (q >> 3);
      mreg[pr][r] = mask[(size_t)Pg * 64 + (q & 7) * 8 + (fr & 7)];
    }
  }

  // spill Q (cols 0-63) and K (cols 64-127) into swizzled [32][64] tables
  #pragma unroll
  for (int n = 0; n < 8; ++n) {
    int col = n * 16 + fr;
    unsigned short* T = (n < 4) ? Qs : Ks;
    unsigned cc = (unsigned)(col & 63);
    #pragma unroll
    for (int m = 0; m < 2; ++m) {
      #pragma unroll
      for (int r = 0; r < 4; ++r) {
        int lr = m * 16 + fq * 4 + r;
        unsigned byte = (unsigned)lr * 128 + ((cc * 2) ^ (((unsigned)(lr & 7)) << 4));
        *(unsigned short*)((unsigned char*)T + byte) = f2bf(acc[m][n][r]);
      }
    }
  }
  LGKM0; __builtin_amdgcn_sched_barrier(0);

  // QK^T for both pixel-pairs (rows 0-15, 16-31 of this wave)
  f32x4 s2[2];
  #pragma unroll
  for (int pr = 0; pr < 2; ++pr) {
    const unsigned rbyte = (unsigned)(pr * 16 + fr) * 128;
    const unsigned xrp = ((unsigned)(fr & 7)) << 4;
    f32x4 s = z4;
    #pragma unroll
    for (int kk = 0; kk < 2; ++kk) {
      const unsigned ko = ((unsigned)(kk * 64 + fq * 16)) ^ xrp;
      bf16x8 qf = *(const bf16x8*)((unsigned char*)Qs + rbyte + ko);
      bf16x8 kf = *(const bf16x8*)((unsigned char*)Ks + rbyte + ko);
      s = __builtin_amdgcn_mfma_f32_16x16x32_bf16(qf, kf, s, 0, 0, 0);
    }
    s2[pr] = s;
  }

  // mask + softmax (8-lane j-groups, in-register)
  float p4[2][4];
  #pragma unroll
  for (int pr = 0; pr < 2; ++pr) {
    #pragma unroll
    for (int r = 0; r < 4; ++r) {
      int q = fq * 4 + r;
      bool valid = (q >> 3) == (fr >> 3);
      float v = valid ? s2[pr][r] * SCALE_ * mreg[pr][r] : -3.0e38f;
      float mx = v;
      mx = fmaxf(mx, __shfl_xor(mx, 1));
      mx = fmaxf(mx, __shfl_xor(mx, 2));
      mx = fmaxf(mx, __shfl_xor(mx, 4));
      float e = __expf(v - mx);
      float sm = e;
      sm += __shfl_xor(sm, 1);
      sm += __shfl_xor(sm, 2);
      sm += __shfl_xor(sm, 4);
      p4[pr][r] = e / sm;
    }
  }
  asm volatile("" ::: "memory");

  // overwrite wave region: VT[64][40] (V^T, both pairs' 32 rows as k=0..31) + Pl per pair
  unsigned short* VT = (unsigned short*)wreg;            // 5120B
  #pragma unroll
  for (int n = 8; n < 12; ++n) {
    int d = (n - 8) * 16 + fr;
    #pragma unroll
    for (int m = 0; m < 2; ++m) {
      ushort4 p;
      p.x = f2bf(acc[m][n][0]); p.y = f2bf(acc[m][n][1]);
      p.z = f2bf(acc[m][n][2]); p.w = f2bf(acc[m][n][3]);
      *(ushort4*)(VT + d * 40 + m * 16 + fq * 4) = p;
    }
  }
  #pragma unroll
  for (int pr = 0; pr < 2; ++pr) {
    unsigned short* Pl = (unsigned short*)(wreg + 5120 + pr * 1280);  // [16][40]
    #pragma unroll
    for (int r = 0; r < 4; ++r) {
      int q = fq * 4 + r;
      bool valid = (q >> 3) == (fr >> 3);
      Pl[q * 40 + pr * 16 + fr] = valid ? f2bf(p4[pr][r]) : (unsigned short)0;
      Pl[q * 40 + (1 - pr) * 16 + fr] = 0;
    }
  }
  LGKM0; __builtin_amdgcn_sched_barrier(0);

  // PV: D[d][q] = sum_j V^T[d][j] P[q][j]  (K=32 over the wave's 32 rows;
  // Pl's zero half selects the right pair)
  #pragma unroll
  for (int pr = 0; pr < 2; ++pr) {
    unsigned char* Plb = wreg + 5120 + pr * 1280;
    #pragma unroll
    for (int dblk = 0; dblk < 4; ++dblk) {
      bf16x8 af = *(const bf16x8*)((unsigned char*)VT +
                    (unsigned)(dblk * 16 + fr) * 80 + (unsigned)fq * 16);
      bf16x8 bf = *(const bf16x8*)(Plb + (unsigned)fr * 80 + (unsigned)fq * 16);
      f32x4 o = {0.f, 0.f, 0.f, 0.f};
      o = __builtin_amdgcn_mfma_f32_16x16x32_bf16(af, bf, o, 0, 0, 0);
      ushort4 pk;
      pk.x = f2bf(o[0]); pk.y = f2bf(o[1]); pk.z = f2bf(o[2]); pk.w = f2bf(o[3]);
      *(ushort4*)(attn_out + (size_t)(r0 + w * 32 + pr * 16 + fr) * 512 +
                  head * 64 + dblk * 16 + fq * 4) = pk;
    }
  }
}

// ---------------- K2: out = attn @ woutT^T + bias (f32 out) ----------------
// dbuf + global_load_lds + XOR-swizzle. 128x128 tile. (proven round-2 version,
// at ~92% of its HBM floor — leave alone)
__global__ __launch_bounds__(256, 2)
void outproj_kernel(const unsigned short* __restrict__ attn,
                    const unsigned short* __restrict__ woutT,
                    const float* __restrict__ bias,
                    float* __restrict__ out) {
  __shared__ __align__(16) unsigned char smem[65536];  // 2 x (A 16KB + B 16KB)
  const int t = threadIdx.x;
  const int lane = t & 63, wave = t >> 6;
  const int wm = wave >> 1, wn = wave & 1;
  const int fr = lane & 15, fq = lane >> 4;
  const int l8 = lane >> 3;
  const int cswz = ((lane & 7) ^ l8) * 8;

  const int per = gridDim.x >> 3;
  const int lin = (blockIdx.x & 7) * per + (blockIdx.x >> 3);
  const int mtile = lin >> 2, nt = lin & 3;
  const int r0 = mtile * 128, n0 = nt * 128;

  f32x4 acc[4][4];
  const f32x4 z4 = {0.f, 0.f, 0.f, 0.f};
  #pragma unroll
  for (int m = 0; m < 4; ++m)
    #pragma unroll
    for (int n = 0; n < 4; ++n) acc[m][n] = z4;

  auto STAGE = [&](int buf, int kt2) {
    unsigned char* base = smem + buf * 32768;
    const int k0 = kt2 * 64;
    const unsigned short* gA = attn  + (size_t)(r0 + l8) * 512 + k0 + cswz;
    const unsigned short* gB = woutT + (size_t)(n0 + l8) * 512 + k0 + cswz;
    #pragma unroll
    for (int i = 0; i < 4; ++i) {
      int c = wave * 4 + i;
      GLL16(gA + (size_t)c * 8 * 512, base + c * 1024);
      GLL16(gB + (size_t)c * 8 * 512, base + 16384 + c * 1024);
    }
  };

  STAGE(0, 0);
  VMCNT(0);
  __syncthreads();
  int cur = 0;

  for (int kt = 0; kt < 8; ++kt) {
    if (kt < 7) STAGE(cur ^ 1, kt + 1);
    unsigned char* Ab = smem + cur * 32768;
    unsigned char* Bb = Ab + 16384;
    const unsigned xr = ((unsigned)(fr & 7)) << 4;
    #pragma unroll
    for (int kk = 0; kk < 2; ++kk) {
      const unsigned ko = ((unsigned)(kk * 64 + fq * 16)) ^ xr;
      bf16x8 a[4], b[4];
      #pragma unroll
      for (int m = 0; m < 4; ++m)
        a[m] = *(const bf16x8*)(Ab + (unsigned)(wm * 64 + m * 16 + fr) * 128 + ko);
      #pragma unroll
      for (int n = 0; n < 4; ++n)
        b[n] = *(const bf16x8*)(Bb + (unsigned)(wn * 64 + n * 16 + fr) * 128 + ko);
      #pragma unroll
      for (int m = 0; m < 4; ++m)
        #pragma unroll
        for (int n = 0; n < 4; ++n)
          acc[m][n] = __builtin_amdgcn_mfma_f32_16x16x32_bf16(a[m], b[n], acc[m][n], 0, 0, 0);
    }
    VMCNT(0);
    __syncthreads();
    cur ^= 1;
  }
  #pragma unroll
  for (int n = 0; n < 4; ++n) {
    int col = n0 + wn * 64 + n * 16 + fr;
    float bv = bias[col];
    #pragma unroll
    for (int m = 0; m < 4; ++m) {
      #pragma unroll
      for (int j = 0; j < 4; ++j) {
        int row = r0 + wm * 64 + m * 16 + fq * 4 + j;
        out[(size_t)row * 512 + col] = acc[m][n][j] + bv;
      }
    }
  }
}

extern "C" void kernel_launch(void* const* d_in, const int* in_sizes, int n_in,
                              void* d_out, int out_size, void* d_ws, size_t ws_size,
                              hipStream_t stream) {
  const float* x    = (const float*)d_in[0];  // [65536][512]
  const float* mask = (const float*)d_in[1];  // [8192][8][8]
  const float* wqkv = (const float*)d_in[2];  // [512][1536]
  const float* wout = (const float*)d_in[3];  // [512][512]
  const float* bias = (const float*)d_in[4];  // [512]
  float* out = (float*)d_out;

  // ws: attn bf16 64MB | wqkvT 1.5MB | woutT 0.5MB | xb bf16 64MB (133.2MB, proven)
  unsigned char* ws = (unsigned char*)d_ws;
  unsigned short* attn  = (unsigned short*)ws;
  unsigned short* wqkvT = (unsigned short*)(ws + 67108864);
  unsigned short* woutT = (unsigned short*)(ws + 67108864 + 1572864);
  unsigned short* xb    = (unsigned short*)(ws + 67108864 + 1572864 + 524288);

  prep_kernel<<<20480, 256, 0, stream>>>(x, wqkv, wout, xb, wqkvT, woutT);
  qkv_attn_kernel<<<4096, 256, 0, stream>>>(xb, mask, wqkvT, attn);
  outproj_kernel<<<2048, 256, 0, stream>>>(attn, woutT, bias, out);
}